// Round 6
// baseline (697.567 us; speedup 1.0000x reference)
//
#include <hip/hip_runtime.h>
#include <hip/hip_bf16.h>

// QuantizedLinear: out[M,N] = inp[M,K] @ (qw[N,K] * scale[N])^T
// M = 4096, K = 4096, N = 12288.
// Pass 1: convert A fp32->bf16, W int32->bf16 into d_ws.
// Pass 2: 256x256 8-wave bf16 GEMM, m201 8-phase schedule:
//   per phase {ds_reads ; 1 half-tile gload_lds ; barrier ; lgkmcnt(0) ;
//   setprio+16 MFMA ; barrier}, 2 K-tiles unrolled per iteration
//   (compile-time buffer indices), ONE counted vmcnt(6) per K-tile
//   (3 half-tiles always in flight, >=5 phases of load latency hiding).
//   T1 XCD swizzle, T2 both-sides XOR swizzle (conflicts measured 0), T5.

#define K_DIM 4096
#define N_DIM 12288

constexpr int BM = 256;
constexpr int BN = 256;
constexpr int BK = 64;
constexpr int NT = K_DIM / BK;   // 64

typedef float  f32x4  __attribute__((ext_vector_type(4)));
typedef int    i32x4  __attribute__((ext_vector_type(4)));
typedef short  bf16x8 __attribute__((ext_vector_type(8)));
typedef unsigned short u16x8 __attribute__((ext_vector_type(8)));
typedef unsigned short u16x4 __attribute__((ext_vector_type(4)));

__device__ __forceinline__ unsigned short f32_to_bf16(float f) {
    unsigned int u = __builtin_bit_cast(unsigned int, f);
    u += 0x7FFFu + ((u >> 16) & 1u);   // round-to-nearest-even
    return (unsigned short)(u >> 16);
}

// ---------------- Pass 1: conversion kernels ----------------

__global__ __launch_bounds__(256)
void cvt_a_kernel(const float* __restrict__ A, unsigned short* __restrict__ Ab, int n8) {
    int stride = gridDim.x * blockDim.x;
    for (int i = blockIdx.x * blockDim.x + threadIdx.x; i < n8; i += stride) {
        const f32x4 a0 = *(const f32x4*)(A + (size_t)i * 8);
        const f32x4 a1 = *(const f32x4*)(A + (size_t)i * 8 + 4);
        u16x8 h;
        h[0] = f32_to_bf16(a0[0]); h[1] = f32_to_bf16(a0[1]);
        h[2] = f32_to_bf16(a0[2]); h[3] = f32_to_bf16(a0[3]);
        h[4] = f32_to_bf16(a1[0]); h[5] = f32_to_bf16(a1[1]);
        h[6] = f32_to_bf16(a1[2]); h[7] = f32_to_bf16(a1[3]);
        *(u16x8*)(Ab + (size_t)i * 8) = h;
    }
}

__global__ __launch_bounds__(256)
void cvt_w_kernel(const int* __restrict__ W, unsigned short* __restrict__ Wb, int n8) {
    int stride = gridDim.x * blockDim.x;
    for (int i = blockIdx.x * blockDim.x + threadIdx.x; i < n8; i += stride) {
        const i32x4 w0 = *(const i32x4*)(W + (size_t)i * 8);
        const i32x4 w1 = *(const i32x4*)(W + (size_t)i * 8 + 4);
        u16x8 h;  // int8 values are exact in bf16
        h[0] = f32_to_bf16((float)w0[0]); h[1] = f32_to_bf16((float)w0[1]);
        h[2] = f32_to_bf16((float)w0[2]); h[3] = f32_to_bf16((float)w0[3]);
        h[4] = f32_to_bf16((float)w1[0]); h[5] = f32_to_bf16((float)w1[1]);
        h[6] = f32_to_bf16((float)w1[2]); h[7] = f32_to_bf16((float)w1[3]);
        *(u16x8*)(Wb + (size_t)i * 8) = h;
    }
}

// ---------------- Pass 2: 256^2 8-phase bf16 GEMM ----------------

__device__ __forceinline__ void gload_lds16(const void* g, void* l) {
    __builtin_amdgcn_global_load_lds(
        (const __attribute__((address_space(1))) unsigned int*)g,
        (__attribute__((address_space(3))) unsigned int*)l,
        16, 0, 0);
}

__global__ __launch_bounds__(512, 2)
void gemm_bf16_256(const unsigned short* __restrict__ Ab,  // [M,K] bf16
                   const unsigned short* __restrict__ Wb,  // [N,K] bf16
                   const float* __restrict__ Sw,           // [N]
                   float* __restrict__ Out,                // [M,N]
                   int M) {
    __shared__ __align__(16) unsigned short As[2][BM * BK];   // 2 x 32 KB
    __shared__ __align__(16) unsigned short Bs[2][BN * BK];   // 2 x 32 KB

    const int tid  = threadIdx.x;
    const int lane = tid & 63;
    const int wid  = tid >> 6;          // 0..7
    const int wm   = wid >> 2;          // 0..1  (128-row half)
    const int wn   = wid & 3;           // 0..3  (64-col strip)

    // T1: XCD swizzle (768 blocks, 96/XCD), column-major in chunk
    const int nwgy = M / BM;                 // 16
    const int nwg  = (N_DIM / BN) * nwgy;    // 768
    const int cpx  = nwg >> 3;               // 96
    const int bid  = blockIdx.x;
    const int swz  = (bid & 7) * cpx + (bid >> 3);
    const int bx   = swz / nwgy;
    const int by   = swz % nwgy;
    const int bm   = by * BM;
    const int bn   = bx * BN;

    // staging: chunk c = j*8+wid -> LDS c*1024B + lane*16B; T2 pre-swizzled global col
    const int srow = wid * 8 + (lane >> 3);
    const int scol = ((lane & 7) ^ (lane >> 3)) * 8;

    #define STG_H(G, grow0, k0, L)                                                  \
        do {                                                                        \
            gload_lds16((G) + (size_t)((grow0) + srow) * K_DIM + (k0) + scol,       \
                        (L) + wid * 512);                                           \
            gload_lds16((G) + (size_t)((grow0) + 64 + srow) * K_DIM + (k0) + scol,  \
                        (L) + (8 + wid) * 512);                                     \
        } while (0)

    f32x4 acc[8][4];
    #pragma unroll
    for (int i = 0; i < 8; ++i)
        #pragma unroll
        for (int j = 0; j < 4; ++j)
            acc[i][j] = (f32x4){0.f, 0.f, 0.f, 0.f};

    const int c0  = lane & 15;
    const int kg  = (lane >> 4) * 8;
    const int rsw = (c0 & 7) * 8;       // read-side swizzle (row&7 == c0&7)

    bf16x8 af[8][2];      // current tile's 8 m-frags x 2 k-slices
    bf16x8 bf0[2][2];     // qn=0 frags (B rows wn*64 + 0..31)
    bf16x8 bf1[2][2];     // qn=1 frags (B rows wn*64 + 32..63)

    const int aoffA = (wm * 128 + c0) * 64;   // per-wave A frag base (elems)
    const int aoffB = (wn * 64 + c0) * 64;    // per-wave B frag base

    #define RD_A(base, BUF, row0)                                                   \
        _Pragma("unroll") for (int mf = 0; mf < 4; ++mf)                            \
        _Pragma("unroll") for (int ks = 0; ks < 2; ++ks)                            \
            af[(base) + mf][ks] = *(const bf16x8*)&As[BUF][aoffA + ((row0) + mf * 16) * 64 + ((ks * 32 + kg) ^ rsw)];

    #define RD_B(dst, BUF, row0)                                                    \
        _Pragma("unroll") for (int nf = 0; nf < 2; ++nf)                            \
        _Pragma("unroll") for (int ks = 0; ks < 2; ++ks)                            \
            (dst)[nf][ks] = *(const bf16x8*)&Bs[BUF][aoffB + ((row0) + nf * 16) * 64 + ((ks * 32 + kg) ^ rsw)];

    #define CLUSTER(qm, qn, BF)                                                     \
        __builtin_amdgcn_s_setprio(1);                                             \
        _Pragma("unroll") for (int ks = 0; ks < 2; ++ks)                            \
        _Pragma("unroll") for (int mf = 0; mf < 4; ++mf)                            \
        _Pragma("unroll") for (int nf = 0; nf < 2; ++nf)                            \
            acc[(qm)*4 + mf][(qn)*2 + nf] = __builtin_amdgcn_mfma_f32_16x16x32_bf16( \
                af[(qm)*4 + mf][ks], (BF)[nf][ks], acc[(qm)*4 + mf][(qn)*2 + nf],    \
                0, 0, 0);                                                            \
        __builtin_amdgcn_s_setprio(0);

    // ---- prologue: tile0 complete + A0,A1,B0 of tile1 (B1(1) issued at ph0 of t=0).
    //      vmcnt(6) -> tile0 landed, exactly 3 half-tiles in flight (steady state). ----
    STG_H(Ab, bm,       0,  &As[0][0]);        // A0(0)
    STG_H(Ab, bm + 128, 0,  &As[0][8192]);     // A1(0)
    STG_H(Wb, bn,       0,  &Bs[0][0]);        // B0(0)
    STG_H(Wb, bn + 128, 0,  &Bs[0][8192]);     // B1(0)
    STG_H(Ab, bm,       BK, &As[1][0]);        // A0(1)
    STG_H(Ab, bm + 128, BK, &As[1][8192]);     // A1(1)
    STG_H(Wb, bn,       BK, &Bs[1][0]);        // B0(1)
    asm volatile("s_waitcnt vmcnt(6)" ::: "memory");
    __builtin_amdgcn_s_barrier();

    // ---- K-loop: 2 K-tiles per iteration, compile-time buffer indices.
    // Per-tile schedule (quadrants qm-fast; A-halves retire ph1, B-halves ph2):
    //   ph0: rd af0-3,bf0 (12) | STG B1(t+1)->nxt.hi | bar | lgkm0 | MFMA(0,0) | bar
    //   ph1: rd af4-7 (8)      |                     | bar | lgkm0 | MFMA(1,0) | bar
    //   ph2: rd bf1 (4)        | STG A0(t+2)->cur.lo | bar | lgkm0 | MFMA(0,1) | bar
    //   ph3:                   | STG A1(t+2)->cur.hi + B0(t+2)->cur.lo
    //        MFMA(1,1) | vmcnt(6) | bar
    // vmcnt(6) leaves exactly {A0,A1,B0}(t+2) in flight; forces B1(t+1)+older. ----
    #define TILE_BODY(T, CUR, NXT)                                                  \
        do {                                                                        \
            const int k1 = ((T) + 1) * BK;                                          \
            const int k2 = ((T) + 2) * BK;                                          \
            /* ph0 */                                                               \
            RD_A(0, CUR, 0);                                                        \
            RD_B(bf0, CUR, 0);                                                      \
            if ((T) + 1 < NT) STG_H(Wb, bn + 128, k1, &Bs[NXT][8192]);              \
            asm volatile("s_waitcnt lgkmcnt(8)");                                   \
            __builtin_amdgcn_s_barrier();                                           \
            asm volatile("s_waitcnt lgkmcnt(0)");                                   \
            CLUSTER(0, 0, bf0);                                                     \
            __builtin_amdgcn_s_barrier();                                           \
            /* ph1 */                                                               \
            RD_A(4, CUR, 64);                                                       \
            __builtin_amdgcn_s_barrier();                                           \
            asm volatile("s_waitcnt lgkmcnt(0)");                                   \
            CLUSTER(1, 0, bf0);                                                     \
            __builtin_amdgcn_s_barrier();                                           \
            /* ph2 */                                                               \
            RD_B(bf1, CUR, 32);                                                     \
            if ((T) + 2 < NT) STG_H(Ab, bm, k2, &As[CUR][0]);                       \
            __builtin_amdgcn_s_barrier();                                           \
            asm volatile("s_waitcnt lgkmcnt(0)");                                   \
            CLUSTER(0, 1, bf1);                                                     \
            __builtin_amdgcn_s_barrier();                                           \
            /* ph3 */                                                               \
            if ((T) + 2 < NT) {                                                     \
                STG_H(Ab, bm + 128, k2, &As[CUR][8192]);                            \
                STG_H(Wb, bn,       k2, &Bs[CUR][0]);                               \
            }                                                                       \
            CLUSTER(1, 1, bf1);                                                     \
            if ((T) < NT - 2) {                                                     \
                asm volatile("s_waitcnt vmcnt(6)" ::: "memory");                    \
            } else if ((T) == NT - 2) {                                             \
                asm volatile("s_waitcnt vmcnt(0)" ::: "memory");                    \
            }                                                                       \
            __builtin_amdgcn_s_barrier();                                           \
        } while (0)

    for (int t = 0; t < NT; t += 2) {
        TILE_BODY(t,     0, 1);
        TILE_BODY(t + 1, 1, 0);
    }
    #undef TILE_BODY
    #undef CLUSTER
    #undef RD_A
    #undef RD_B
    #undef STG_H

    // ---- epilogue: C/D col = lane&15 (B row), row = (lane>>4)*4 + j (A row) ----
    const int r0 = (lane >> 4) * 4;
    #pragma unroll
    for (int n = 0; n < 4; ++n) {
        const int col = bn + wn * 64 + n * 16 + c0;
        const float s = Sw[col];
        #pragma unroll
        for (int m = 0; m < 8; ++m) {
            const int rowb = bm + wm * 128 + m * 16 + r0;
            #pragma unroll
            for (int j = 0; j < 4; ++j)
                Out[(size_t)(rowb + j) * N_DIM + col] = acc[m][n][j] * s;
        }
    }
}

// ---------------- Fallback (fused, if ws too small) ----------------

constexpr int FBM = 128, FBN = 128, FBK = 64, FPAD = 8;

__global__ __launch_bounds__(256)
void qlinear_fused_kernel(const float* __restrict__ A, const int* __restrict__ Wq,
                          const float* __restrict__ Sw, float* __restrict__ Out, int M) {
    __shared__ unsigned short Asf[FBM][FBK + FPAD];
    __shared__ unsigned short Bsf[FBN][FBK + FPAD];
    const int tid  = threadIdx.x;
    const int lane = tid & 63;
    const int wid  = tid >> 6;
    const int wm   = wid >> 1;
    const int wn   = wid & 1;
    const int bm = blockIdx.y * FBM;
    const int bn = blockIdx.x * FBN;
    const int rowT = tid >> 4;
    const int kq   = tid & 15;
    f32x4 acc[4][4];
    #pragma unroll
    for (int i = 0; i < 4; ++i)
        #pragma unroll
        for (int j = 0; j < 4; ++j) acc[i][j] = (f32x4){0.f,0.f,0.f,0.f};
    const int c0 = lane & 15;
    const int kg = (lane >> 4) * 8;
    for (int k0 = 0; k0 < K_DIM; k0 += FBK) {
        #pragma unroll
        for (int it = 0; it < 8; ++it) {
            const int r = it * 16 + rowT;
            const f32x4 a4 = *(const f32x4*)(A + (size_t)(bm + r) * K_DIM + k0 + kq * 4);
            u16x4 h;
            h[0]=f32_to_bf16(a4[0]); h[1]=f32_to_bf16(a4[1]);
            h[2]=f32_to_bf16(a4[2]); h[3]=f32_to_bf16(a4[3]);
            *(u16x4*)&Asf[r][kq*4] = h;
        }
        #pragma unroll
        for (int it = 0; it < 8; ++it) {
            const int r = it * 16 + rowT;
            const i32x4 w4 = *(const i32x4*)(Wq + (size_t)(bn + r) * K_DIM + k0 + kq * 4);
            u16x4 h;
            h[0]=f32_to_bf16((float)w4[0]); h[1]=f32_to_bf16((float)w4[1]);
            h[2]=f32_to_bf16((float)w4[2]); h[3]=f32_to_bf16((float)w4[3]);
            *(u16x4*)&Bsf[r][kq*4] = h;
        }
        __syncthreads();
        #pragma unroll
        for (int ks = 0; ks < 2; ++ks) {
            const int kk = ks * 32 + kg;
            bf16x8 af2[4], bfr[4];
            #pragma unroll
            for (int mf = 0; mf < 4; ++mf)
                af2[mf] = *(const bf16x8*)&Asf[wm*64 + mf*16 + c0][kk];
            #pragma unroll
            for (int nf = 0; nf < 4; ++nf)
                bfr[nf] = *(const bf16x8*)&Bsf[wn*64 + nf*16 + c0][kk];
            #pragma unroll
            for (int mf = 0; mf < 4; ++mf)
                #pragma unroll
                for (int nf = 0; nf < 4; ++nf)
                    acc[mf][nf] = __builtin_amdgcn_mfma_f32_16x16x32_bf16(
                        af2[mf], bfr[nf], acc[mf][nf], 0, 0, 0);
        }
        __syncthreads();
    }
    const int r0 = (lane >> 4) * 4;
    #pragma unroll
    for (int nf = 0; nf < 4; ++nf) {
        const int col = bn + wn*64 + nf*16 + c0;
        const float s = Sw[col];
        #pragma unroll
        for (int mf = 0; mf < 4; ++mf) {
            const int rowb = bm + wm*64 + mf*16 + r0;
            #pragma unroll
            for (int j = 0; j < 4; ++j)
                Out[(size_t)(rowb + j) * N_DIM + col] = acc[mf][nf][j] * s;
        }
    }
}

extern "C" void kernel_launch(void* const* d_in, const int* in_sizes, int n_in,
                              void* d_out, int out_size, void* d_ws, size_t ws_size,
                              hipStream_t stream) {
    const float* inp = (const float*)d_in[0];
    const int*   qw  = (const int*)d_in[1];
    const float* sw  = (const float*)d_in[2];
    float*       out = (float*)d_out;

    const int M = in_sizes[0] / K_DIM;                         // 4096
    const size_t nA = (size_t)M * K_DIM;
    const size_t nW = (size_t)N_DIM * K_DIM;
    const size_t need = (nA + nW) * sizeof(unsigned short);    // 128 MiB

    if (ws_size >= need && (M % BM) == 0) {
        unsigned short* Abf = (unsigned short*)d_ws;
        unsigned short* Wbf = Abf + nA;
        cvt_a_kernel<<<2048, 256, 0, stream>>>(inp, Abf, (int)(nA / 8));
        cvt_w_kernel<<<2048, 256, 0, stream>>>(qw, Wbf, (int)(nW / 8));
        dim3 grid((N_DIM / BN) * (M / BM));                    // 768
        gemm_bf16_256<<<grid, 512, 0, stream>>>(Abf, Wbf, sw, out, M);
    } else {
        dim3 grid(N_DIM / FBN, M / FBM);
        qlinear_fused_kernel<<<grid, 256, 0, stream>>>(inp, qw, sw, out, M);
    }
}

// Round 7
// 562.710 us; speedup vs baseline: 1.2397x; 1.2397x over previous
//
#include <hip/hip_runtime.h>
#include <hip/hip_bf16.h>

// QuantizedLinear: out[M,N] = inp[M,K] @ (qw[N,K] * scale[N])^T
// M = 4096, K = 4096, N = 12288.
// Pass 1: convert A fp32->bf16, W int32->bf16 into d_ws.
// Pass 2: 256x256 8-wave bf16 GEMM. Software-pipelined phases:
//   reads issued in phase p are consumed by the MFMA cluster of phase p+1,
//   with NO explicit lgkm waits / sched_barriers -> compiler emits counted
//   lgkmcnt, so the LDS drain overlaps the current cluster (T3 mechanism).
//   1 raw barrier per phase; single counted vmcnt(2) per K-tile at ph2-end
//   (certifies tile t+1 before ph3's next-buffer reads).
//   T1 XCD swizzle, T2 both-sides XOR swizzle, T5 setprio.

#define K_DIM 4096
#define N_DIM 12288

constexpr int BM = 256;
constexpr int BN = 256;
constexpr int BK = 64;
constexpr int NT = K_DIM / BK;   // 64

typedef float  f32x4  __attribute__((ext_vector_type(4)));
typedef int    i32x4  __attribute__((ext_vector_type(4)));
typedef short  bf16x8 __attribute__((ext_vector_type(8)));
typedef unsigned short u16x8 __attribute__((ext_vector_type(8)));
typedef unsigned short u16x4 __attribute__((ext_vector_type(4)));

__device__ __forceinline__ unsigned short f32_to_bf16(float f) {
    unsigned int u = __builtin_bit_cast(unsigned int, f);
    u += 0x7FFFu + ((u >> 16) & 1u);   // round-to-nearest-even
    return (unsigned short)(u >> 16);
}

// ---------------- Pass 1: conversion kernels ----------------

__global__ __launch_bounds__(256)
void cvt_a_kernel(const float* __restrict__ A, unsigned short* __restrict__ Ab, int n8) {
    int stride = gridDim.x * blockDim.x;
    for (int i = blockIdx.x * blockDim.x + threadIdx.x; i < n8; i += stride) {
        const f32x4 a0 = *(const f32x4*)(A + (size_t)i * 8);
        const f32x4 a1 = *(const f32x4*)(A + (size_t)i * 8 + 4);
        u16x8 h;
        h[0] = f32_to_bf16(a0[0]); h[1] = f32_to_bf16(a0[1]);
        h[2] = f32_to_bf16(a0[2]); h[3] = f32_to_bf16(a0[3]);
        h[4] = f32_to_bf16(a1[0]); h[5] = f32_to_bf16(a1[1]);
        h[6] = f32_to_bf16(a1[2]); h[7] = f32_to_bf16(a1[3]);
        *(u16x8*)(Ab + (size_t)i * 8) = h;
    }
}

__global__ __launch_bounds__(256)
void cvt_w_kernel(const int* __restrict__ W, unsigned short* __restrict__ Wb, int n8) {
    int stride = gridDim.x * blockDim.x;
    for (int i = blockIdx.x * blockDim.x + threadIdx.x; i < n8; i += stride) {
        const i32x4 w0 = *(const i32x4*)(W + (size_t)i * 8);
        const i32x4 w1 = *(const i32x4*)(W + (size_t)i * 8 + 4);
        u16x8 h;  // int8 values are exact in bf16
        h[0] = f32_to_bf16((float)w0[0]); h[1] = f32_to_bf16((float)w0[1]);
        h[2] = f32_to_bf16((float)w0[2]); h[3] = f32_to_bf16((float)w0[3]);
        h[4] = f32_to_bf16((float)w1[0]); h[5] = f32_to_bf16((float)w1[1]);
        h[6] = f32_to_bf16((float)w1[2]); h[7] = f32_to_bf16((float)w1[3]);
        *(u16x8*)(Wb + (size_t)i * 8) = h;
    }
}

// ---------------- Pass 2: 256^2 pipelined bf16 GEMM ----------------

__device__ __forceinline__ void gload_lds16(const void* g, void* l) {
    __builtin_amdgcn_global_load_lds(
        (const __attribute__((address_space(1))) unsigned int*)g,
        (__attribute__((address_space(3))) unsigned int*)l,
        16, 0, 0);
}

__global__ __launch_bounds__(512, 2)
void gemm_bf16_256(const unsigned short* __restrict__ Ab,  // [M,K] bf16
                   const unsigned short* __restrict__ Wb,  // [N,K] bf16
                   const float* __restrict__ Sw,           // [N]
                   float* __restrict__ Out,                // [M,N]
                   int M) {
    __shared__ __align__(16) unsigned short As[2][BM * BK];   // 2 x 32 KB
    __shared__ __align__(16) unsigned short Bs[2][BN * BK];   // 2 x 32 KB

    const int tid  = threadIdx.x;
    const int lane = tid & 63;
    const int wid  = tid >> 6;          // 0..7
    const int wm   = wid >> 2;          // 0..1  (128-row half)
    const int wn   = wid & 3;           // 0..3  (64-col strip)

    // T1: XCD swizzle (768 blocks, 96/XCD), column-major in chunk
    const int nwgy = M / BM;                 // 16
    const int nwg  = (N_DIM / BN) * nwgy;    // 768
    const int cpx  = nwg >> 3;               // 96
    const int bid  = blockIdx.x;
    const int swz  = (bid & 7) * cpx + (bid >> 3);
    const int bx   = swz / nwgy;
    const int by   = swz % nwgy;
    const int bm   = by * BM;
    const int bn   = bx * BN;

    // staging: chunk c = j*8+wid -> LDS c*1024B + lane*16B; T2 pre-swizzled global col
    const int srow = wid * 8 + (lane >> 3);
    const int scol = ((lane & 7) ^ (lane >> 3)) * 8;

    #define STG_H(G, grow0, k0, L)                                                  \
        do {                                                                        \
            gload_lds16((G) + (size_t)((grow0) + srow) * K_DIM + (k0) + scol,       \
                        (L) + wid * 512);                                           \
            gload_lds16((G) + (size_t)((grow0) + 64 + srow) * K_DIM + (k0) + scol,  \
                        (L) + (8 + wid) * 512);                                     \
        } while (0)

    f32x4 acc[8][4];
    #pragma unroll
    for (int i = 0; i < 8; ++i)
        #pragma unroll
        for (int j = 0; j < 4; ++j)
            acc[i][j] = (f32x4){0.f, 0.f, 0.f, 0.f};

    const int c0  = lane & 15;
    const int kg  = (lane >> 4) * 8;
    const int rsw = (c0 & 7) * 8;       // read-side swizzle (row&7 == c0&7)

    bf16x8 af[8][2];      // current tile's 8 m-frags x 2 k-slices
    bf16x8 bf0[2][2];     // B rows wn*64 + 0..31
    bf16x8 bf1[2][2];     // B rows wn*64 + 32..63

    #define RD_A(base, src, row0)                                                   \
        _Pragma("unroll") for (int mf = 0; mf < 4; ++mf)                            \
        _Pragma("unroll") for (int ks = 0; ks < 2; ++ks)                            \
            af[(base) + mf][ks] = *(const bf16x8*)&(src)[((row0) + mf * 16) * 64 + ((ks * 32 + kg) ^ rsw)];

    #define RD_B(dst, src, row0)                                                    \
        _Pragma("unroll") for (int nf = 0; nf < 2; ++nf)                            \
        _Pragma("unroll") for (int ks = 0; ks < 2; ++ks)                            \
            (dst)[nf][ks] = *(const bf16x8*)&(src)[((row0) + nf * 16) * 64 + ((ks * 32 + kg) ^ rsw)];

    #define CLUSTER(qm, qn, BF)                                                     \
        __builtin_amdgcn_s_setprio(1);                                             \
        _Pragma("unroll") for (int ks = 0; ks < 2; ++ks)                            \
        _Pragma("unroll") for (int mf = 0; mf < 4; ++mf)                            \
        _Pragma("unroll") for (int nf = 0; nf < 2; ++nf)                            \
            acc[(qm)*4 + mf][(qn)*2 + nf] = __builtin_amdgcn_mfma_f32_16x16x32_bf16( \
                af[(qm)*4 + mf][ks], (BF)[nf][ks], acc[(qm)*4 + mf][(qn)*2 + nf],    \
                0, 0, 0);                                                            \
        __builtin_amdgcn_s_setprio(0);

    // ---- prologue: tile0 (4 halves) + A0(1),A1(1). vmcnt(4) -> tile0 landed,
    //      A(1) stays in flight. Then read t=0's first frags (af0-3, bf0). ----
    STG_H(Ab, bm,       0,  &As[0][0]);        // A0(0)
    STG_H(Ab, bm + 128, 0,  &As[0][8192]);     // A1(0)
    STG_H(Wb, bn,       0,  &Bs[0][0]);        // B0(0)
    STG_H(Wb, bn + 128, 0,  &Bs[0][8192]);     // B1(0)
    STG_H(Ab, bm,       BK, &As[1][0]);        // A0(1)
    STG_H(Ab, bm + 128, BK, &As[1][8192]);     // A1(1)
    asm volatile("s_waitcnt vmcnt(4)" ::: "memory");
    __builtin_amdgcn_s_barrier();

    {
        const unsigned short* A0f = &As[0][(wm * 128 + c0) * 64];
        const unsigned short* B0f = &Bs[0][(wn * 64 + c0) * 64];
        RD_A(0, A0f, 0);        // af0-3(t=0)
        RD_B(bf0, B0f, 0);      // bf0(t=0)
    }

    // ---- K-loop. Quadrant order (0,0),(1,0),(0,1),(1,1).
    // Reads one phase ahead of consumption (compiler emits counted lgkmcnt):
    //   ph0: rd af4-7(t)          | STG B0(t+1) | MFMA(0,0)[af0-3,bf0] | bar
    //   ph1: rd bf1(t)            | STG B1(t+1) | MFMA(1,0)[af4-7,bf0] | bar
    //   ph2:                      | STG A0(t+2) | MFMA(0,1)[af0-3,bf1]
    //        vmcnt(2): forces A1(t+1),B0(t+1),B1(t+1); leaves A0(t+2) | bar
    //   ph3: rd af0-3,bf0 (t+1)   | STG A1(t+2) | MFMA(1,1)[af4-7,bf1] | bar
    // Hazards: every region's reads complete >=2 barriers before its overwrite;
    // ph3's next-buffer reads certified by ph2's vmcnt+barrier. ----
    for (int t = 0; t < NT; ++t) {
        const int cur = t & 1;
        const unsigned short* Ac = &As[cur][(wm * 128 + c0) * 64];
        const unsigned short* Bc = &Bs[cur][(wn * 64 + c0) * 64];
        const unsigned short* An = &As[cur ^ 1][(wm * 128 + c0) * 64];
        const unsigned short* Bn = &Bs[cur ^ 1][(wn * 64 + c0) * 64];
        unsigned short* Bdst = &Bs[cur ^ 1][0];   // B(t+1)
        unsigned short* Adst = &As[cur][0];       // A(t+2)
        const int k1 = (t + 1) * BK;
        const int k2 = (t + 2) * BK;

        // ph0
        RD_A(4, Ac, 64);
        if (t + 1 < NT) STG_H(Wb, bn, k1, Bdst);
        CLUSTER(0, 0, bf0);
        __builtin_amdgcn_s_barrier();

        // ph1
        RD_B(bf1, Bc, 32);
        if (t + 1 < NT) STG_H(Wb, bn + 128, k1, Bdst + 8192);
        CLUSTER(1, 0, bf0);
        __builtin_amdgcn_s_barrier();

        // ph2
        if (t + 2 < NT) STG_H(Ab, bm, k2, Adst);
        CLUSTER(0, 1, bf1);
        if (t < NT - 2) {
            asm volatile("s_waitcnt vmcnt(2)" ::: "memory");
        } else if (t == NT - 2) {
            asm volatile("s_waitcnt vmcnt(0)" ::: "memory");
        }
        __builtin_amdgcn_s_barrier();

        // ph3
        if (t + 2 < NT) STG_H(Ab, bm + 128, k2, Adst + 8192);
        if (t + 1 < NT) {
            RD_A(0, An, 0);
            RD_B(bf0, Bn, 0);
        }
        CLUSTER(1, 1, bf1);
        __builtin_amdgcn_s_barrier();
    }
    #undef CLUSTER
    #undef RD_A
    #undef RD_B
    #undef STG_H

    // ---- epilogue: C/D col = lane&15 (B row), row = (lane>>4)*4 + j (A row) ----
    const int r0 = (lane >> 4) * 4;
    #pragma unroll
    for (int n = 0; n < 4; ++n) {
        const int col = bn + wn * 64 + n * 16 + c0;
        const float s = Sw[col];
        #pragma unroll
        for (int m = 0; m < 8; ++m) {
            const int rowb = bm + wm * 128 + m * 16 + r0;
            #pragma unroll
            for (int j = 0; j < 4; ++j)
                Out[(size_t)(rowb + j) * N_DIM + col] = acc[m][n][j] * s;
        }
    }
}

// ---------------- Fallback (fused, if ws too small) ----------------

constexpr int FBM = 128, FBN = 128, FBK = 64, FPAD = 8;

__global__ __launch_bounds__(256)
void qlinear_fused_kernel(const float* __restrict__ A, const int* __restrict__ Wq,
                          const float* __restrict__ Sw, float* __restrict__ Out, int M) {
    __shared__ unsigned short Asf[FBM][FBK + FPAD];
    __shared__ unsigned short Bsf[FBN][FBK + FPAD];
    const int tid  = threadIdx.x;
    const int lane = tid & 63;
    const int wid  = tid >> 6;
    const int wm   = wid >> 1;
    const int wn   = wid & 1;
    const int bm = blockIdx.y * FBM;
    const int bn = blockIdx.x * FBN;
    const int rowT = tid >> 4;
    const int kq   = tid & 15;
    f32x4 acc[4][4];
    #pragma unroll
    for (int i = 0; i < 4; ++i)
        #pragma unroll
        for (int j = 0; j < 4; ++j) acc[i][j] = (f32x4){0.f,0.f,0.f,0.f};
    const int c0 = lane & 15;
    const int kg = (lane >> 4) * 8;
    for (int k0 = 0; k0 < K_DIM; k0 += FBK) {
        #pragma unroll
        for (int it = 0; it < 8; ++it) {
            const int r = it * 16 + rowT;
            const f32x4 a4 = *(const f32x4*)(A + (size_t)(bm + r) * K_DIM + k0 + kq * 4);
            u16x4 h;
            h[0]=f32_to_bf16(a4[0]); h[1]=f32_to_bf16(a4[1]);
            h[2]=f32_to_bf16(a4[2]); h[3]=f32_to_bf16(a4[3]);
            *(u16x4*)&Asf[r][kq*4] = h;
        }
        #pragma unroll
        for (int it = 0; it < 8; ++it) {
            const int r = it * 16 + rowT;
            const i32x4 w4 = *(const i32x4*)(Wq + (size_t)(bn + r) * K_DIM + k0 + kq * 4);
            u16x4 h;
            h[0]=f32_to_bf16((float)w4[0]); h[1]=f32_to_bf16((float)w4[1]);
            h[2]=f32_to_bf16((float)w4[2]); h[3]=f32_to_bf16((float)w4[3]);
            *(u16x4*)&Bsf[r][kq*4] = h;
        }
        __syncthreads();
        #pragma unroll
        for (int ks = 0; ks < 2; ++ks) {
            const int kk = ks * 32 + kg;
            bf16x8 af2[4], bfr[4];
            #pragma unroll
            for (int mf = 0; mf < 4; ++mf)
                af2[mf] = *(const bf16x8*)&Asf[wm*64 + mf*16 + c0][kk];
            #pragma unroll
            for (int nf = 0; nf < 4; ++nf)
                bfr[nf] = *(const bf16x8*)&Bsf[wn*64 + nf*16 + c0][kk];
            #pragma unroll
            for (int mf = 0; mf < 4; ++mf)
                #pragma unroll
                for (int nf = 0; nf < 4; ++nf)
                    acc[mf][nf] = __builtin_amdgcn_mfma_f32_16x16x32_bf16(
                        af2[mf], bfr[nf], acc[mf][nf], 0, 0, 0);
        }
        __syncthreads();
    }
    const int r0 = (lane >> 4) * 4;
    #pragma unroll
    for (int nf = 0; nf < 4; ++nf) {
        const int col = bn + wn*64 + nf*16 + c0;
        const float s = Sw[col];
        #pragma unroll
        for (int mf = 0; mf < 4; ++mf) {
            const int rowb = bm + wm*64 + mf*16 + r0;
            #pragma unroll
            for (int j = 0; j < 4; ++j)
                Out[(size_t)(rowb + j) * N_DIM + col] = acc[mf][nf][j] * s;
        }
    }
}

extern "C" void kernel_launch(void* const* d_in, const int* in_sizes, int n_in,
                              void* d_out, int out_size, void* d_ws, size_t ws_size,
                              hipStream_t stream) {
    const float* inp = (const float*)d_in[0];
    const int*   qw  = (const int*)d_in[1];
    const float* sw  = (const float*)d_in[2];
    float*       out = (float*)d_out;

    const int M = in_sizes[0] / K_DIM;                         // 4096
    const size_t nA = (size_t)M * K_DIM;
    const size_t nW = (size_t)N_DIM * K_DIM;
    const size_t need = (nA + nW) * sizeof(unsigned short);    // 128 MiB

    if (ws_size >= need && (M % BM) == 0) {
        unsigned short* Abf = (unsigned short*)d_ws;
        unsigned short* Wbf = Abf + nA;
        cvt_a_kernel<<<2048, 256, 0, stream>>>(inp, Abf, (int)(nA / 8));
        cvt_w_kernel<<<2048, 256, 0, stream>>>(qw, Wbf, (int)(nW / 8));
        dim3 grid((N_DIM / BN) * (M / BM));                    // 768
        gemm_bf16_256<<<grid, 512, 0, stream>>>(Abf, Wbf, sw, out, M);
    } else {
        dim3 grid(N_DIM / FBN, M / FBM);
        qlinear_fused_kernel<<<grid, 256, 0, stream>>>(inp, qw, sw, out, M);
    }
}

// Round 8
// 310.831 us; speedup vs baseline: 2.2442x; 1.8103x over previous
//
#include <hip/hip_runtime.h>
#include <hip/hip_bf16.h>

// QuantizedLinear: out[M,N] = inp[M,K] @ (qw[N,K] * scale[N])^T
// M = 4096, K = 4096, N = 12288.
// INT8 path:
//   Pass 1a: per-row absmax-quantize A fp32 -> int8 (+ row scale Ra[m]).
//   Pass 1b: W int32 -> int8 (exact).
//   Pass 2:  256x256 8-wave i8 GEMM, mfma_i32_16x16x64_i8, BK=128 elems
//            (byte-identical LDS geometry to the bf16 BK=64 kernel),
//            round-4 schedule (best measured), T1 XCD swizzle, T2 both-sides
//            XOR swizzle, T5 setprio, global_load_lds w=16.
//   Epilogue: out = (float)acc * scale_w[col] * Ra[row].

#define K_DIM 4096
#define N_DIM 12288

constexpr int BM = 256;
constexpr int BN = 256;
constexpr int BKB = 128;          // K-tile in elements == bytes (i8)
constexpr int NT = K_DIM / BKB;   // 32

typedef float  f32x4  __attribute__((ext_vector_type(4)));
typedef int    i32x4  __attribute__((ext_vector_type(4)));
typedef short  bf16x8 __attribute__((ext_vector_type(8)));
typedef unsigned short u16x4 __attribute__((ext_vector_type(4)));

__device__ __forceinline__ unsigned short f32_to_bf16(float f) {
    unsigned int u = __builtin_bit_cast(unsigned int, f);
    u += 0x7FFFu + ((u >> 16) & 1u);
    return (unsigned short)(u >> 16);
}

// ---------------- Pass 1a: per-row quantize A -> int8 ----------------
// One block per row; each thread owns 16 contiguous floats.

__global__ __launch_bounds__(256)
void quant_a_kernel(const float* __restrict__ A,
                    signed char* __restrict__ Aq,
                    float* __restrict__ Ra) {
    const int row  = blockIdx.x;
    const int tid  = threadIdx.x;
    const int lane = tid & 63;
    const int wid  = tid >> 6;
    const float* arow = A + (size_t)row * K_DIM;
    const int base = tid * 16;

    f32x4 v[4];
    #pragma unroll
    for (int i = 0; i < 4; ++i)
        v[i] = *(const f32x4*)(arow + base + i * 4);

    float mx = 0.f;
    #pragma unroll
    for (int i = 0; i < 4; ++i)
        #pragma unroll
        for (int j = 0; j < 4; ++j)
            mx = fmaxf(mx, fabsf(v[i][j]));

    #pragma unroll
    for (int off = 32; off > 0; off >>= 1)
        mx = fmaxf(mx, __shfl_xor(mx, off));

    __shared__ float wmax[4];
    if (lane == 0) wmax[wid] = mx;
    __syncthreads();
    mx = fmaxf(fmaxf(wmax[0], wmax[1]), fmaxf(wmax[2], wmax[3]));

    const float inv = (mx > 0.f) ? (127.0f / mx) : 0.f;
    if (tid == 0) Ra[row] = mx * (1.0f / 127.0f);

    int p[4];
    #pragma unroll
    for (int i = 0; i < 4; ++i) {
        int b0 = (int)rintf(v[i][0] * inv);
        int b1 = (int)rintf(v[i][1] * inv);
        int b2 = (int)rintf(v[i][2] * inv);
        int b3 = (int)rintf(v[i][3] * inv);
        p[i] = (b0 & 255) | ((b1 & 255) << 8) | ((b2 & 255) << 16) | (b3 << 24);
    }
    *(i32x4*)(Aq + (size_t)row * K_DIM + base) = *(i32x4*)p;
}

// ---------------- Pass 1b: W int32 -> int8 (exact) ----------------

__global__ __launch_bounds__(256)
void cvt_w8_kernel(const int* __restrict__ W, signed char* __restrict__ Wq, int n16) {
    int stride = gridDim.x * blockDim.x;
    for (int i = blockIdx.x * blockDim.x + threadIdx.x; i < n16; i += stride) {
        const int* src = W + (size_t)i * 16;
        int p[4];
        #pragma unroll
        for (int q = 0; q < 4; ++q) {
            const i32x4 w = *(const i32x4*)(src + q * 4);
            p[q] = (w[0] & 255) | ((w[1] & 255) << 8) | ((w[2] & 255) << 16) | (w[3] << 24);
        }
        *(i32x4*)(Wq + (size_t)i * 16) = *(i32x4*)p;
    }
}

// ---------------- Pass 2: 256^2 i8 GEMM (round-4 schedule) ----------------

__device__ __forceinline__ void gload_lds16(const void* g, void* l) {
    __builtin_amdgcn_global_load_lds(
        (const __attribute__((address_space(1))) unsigned int*)g,
        (__attribute__((address_space(3))) unsigned int*)l,
        16, 0, 0);
}

__global__ __launch_bounds__(512, 2)
void gemm_i8_256(const signed char* __restrict__ Aq,   // [M,K] i8
                 const signed char* __restrict__ Wq,   // [N,K] i8
                 const float* __restrict__ Sw,         // [N]
                 const float* __restrict__ Ra,         // [M]
                 float* __restrict__ Out,              // [M,N]
                 int M) {
    // 2 K-tile buffers: A 2x32KB + B 2x32KB = 128 KiB (bytes)
    __shared__ __align__(16) unsigned char As8[2][BM * BKB];
    __shared__ __align__(16) unsigned char Bs8[2][BN * BKB];

    const int tid  = threadIdx.x;
    const int lane = tid & 63;
    const int wid  = tid >> 6;          // 0..7
    const int wm   = wid >> 2;          // 0..1  (128-row half)
    const int wn   = wid & 3;           // 0..3  (64-col strip)

    // T1: XCD swizzle (768 blocks, 96/XCD), column-major within chunk
    const int nwgy = M / BM;                 // 16
    const int nwg  = (N_DIM / BN) * nwgy;    // 768
    const int cpx  = nwg >> 3;               // 96
    const int bid  = blockIdx.x;
    const int swz  = (bid & 7) * cpx + (bid >> 3);
    const int bx   = swz / nwgy;
    const int by   = swz % nwgy;
    const int bm   = by * BM;
    const int bn   = bx * BN;

    // staging (byte-identical to bf16 BK=64 case): chunk c = j*8+wid,
    // lane writes c*1024B + lane*16B -> row c*8+(lane>>3), colB (lane&7)*16.
    // T2 rule #21: pre-swizzle the GLOBAL col byte by row&7; LDS stays linear.
    const int srow  = wid * 8 + (lane >> 3);
    const int scolB = ((lane & 7) ^ (lane >> 3)) * 16;      // bytes

    #define STG_H(G, grow0, k0B, L)                                                 \
        do {                                                                        \
            gload_lds16((G) + (size_t)((grow0) + srow) * K_DIM + (k0B) + scolB,     \
                        (L) + wid * 1024);                                          \
            gload_lds16((G) + (size_t)((grow0) + 64 + srow) * K_DIM + (k0B) + scolB,\
                        (L) + 8192 + wid * 1024);                                   \
        } while (0)

    i32x4 acc[8][4];
    #pragma unroll
    for (int i = 0; i < 8; ++i)
        #pragma unroll
        for (int j = 0; j < 4; ++j)
            acc[i][j] = (i32x4){0, 0, 0, 0};

    const int c0   = lane & 15;
    const int kgB  = (lane >> 4) * 16;     // byte offset of lane's K-group
    const int rswB = (c0 & 7) * 16;        // read-side swizzle (row&7 == c0&7)

    i32x4 af[8][2];      // 8 m-frags x 2 k-slices (each 16 i8 = 16B)
    i32x4 bf0[2][2];     // B rows wn*64 + 0..31
    i32x4 bf1[2][2];     // B rows wn*64 + 32..63

    const int aoffA = (wm * 128 + c0) * BKB;   // byte base of wave's A rows
    const int aoffB = (wn * 64 + c0) * BKB;

    #define RD_A(base, BUF, row0)                                                   \
        _Pragma("unroll") for (int mf = 0; mf < 4; ++mf)                            \
        _Pragma("unroll") for (int ks = 0; ks < 2; ++ks)                            \
            af[(base) + mf][ks] = *(const i32x4*)&As8[BUF][aoffA + ((row0) + mf * 16) * BKB + ((ks * 64 + kgB) ^ rswB)];

    #define RD_B(dst, BUF, row0)                                                    \
        _Pragma("unroll") for (int nf = 0; nf < 2; ++nf)                            \
        _Pragma("unroll") for (int ks = 0; ks < 2; ++ks)                            \
            (dst)[nf][ks] = *(const i32x4*)&Bs8[BUF][aoffB + ((row0) + nf * 16) * BKB + ((ks * 64 + kgB) ^ rswB)];

    #define CLUSTER(qm, qn, BF)                                                     \
        __builtin_amdgcn_s_setprio(1);                                             \
        _Pragma("unroll") for (int ks = 0; ks < 2; ++ks)                            \
        _Pragma("unroll") for (int mf = 0; mf < 4; ++mf)                            \
        _Pragma("unroll") for (int nf = 0; nf < 2; ++nf)                            \
            acc[(qm)*4 + mf][(qn)*2 + nf] = __builtin_amdgcn_mfma_i32_16x16x64_i8(  \
                af[(qm)*4 + mf][ks], (BF)[nf][ks], acc[(qm)*4 + mf][(qn)*2 + nf],   \
                0, 0, 0);                                                            \
        __builtin_amdgcn_s_setprio(0);

    // ---- prologue: tile0 complete + A-halves of tile1; 4 loads stay in flight ----
    STG_H(Aq, bm,       0,   &As8[0][0]);
    STG_H(Aq, bm + 128, 0,   &As8[0][16384]);
    STG_H(Wq, bn,       0,   &Bs8[0][0]);
    STG_H(Wq, bn + 128, 0,   &Bs8[0][16384]);
    STG_H(Aq, bm,       BKB, &As8[1][0]);
    STG_H(Aq, bm + 128, BKB, &As8[1][16384]);
    asm volatile("s_waitcnt vmcnt(4)" ::: "memory");   // tile0 landed; A(1) in flight
    __builtin_amdgcn_s_barrier();

    // ---- K-loop: round-4 schedule, i8 flavor. NT = 32. ----
    for (int t = 0; t < NT; ++t) {
        const int cur = t & 1;
        unsigned char* Bnx  = &Bs8[cur ^ 1][0];   // B(t+1)
        unsigned char* Acur = &As8[cur][0];       // A(t+2)
        const int k1 = (t + 1) * BKB;
        const int k2 = (t + 2) * BKB;

        // ph0: read af0-3 + bf0; stage B0(t+1)
        RD_A(0, cur, 0);
        RD_B(bf0, cur, 0);
        if (t + 1 < NT) STG_H(Wq, bn, k1, Bnx);
        __builtin_amdgcn_s_barrier();
        asm volatile("s_waitcnt lgkmcnt(0)");
        CLUSTER(0, 0, bf0);
        __builtin_amdgcn_s_barrier();

        // ph1: read af4-7; stage B1(t+1). A(cur) reads all retired after this phase.
        RD_A(4, cur, 64);
        if (t + 1 < NT) STG_H(Wq, bn + 128, k1, Bnx + 16384);
        __builtin_amdgcn_s_barrier();
        asm volatile("s_waitcnt lgkmcnt(0)");
        CLUSTER(1, 0, bf0);
        __builtin_amdgcn_s_barrier();

        // ph2: read bf1; stage A0(t+2) into cur (safe post-ph1 barrier)
        RD_B(bf1, cur, 32);
        if (t + 2 < NT) STG_H(Aq, bm, k2, Acur);
        __builtin_amdgcn_s_barrier();
        asm volatile("s_waitcnt lgkmcnt(0)");
        CLUSTER(0, 1, bf1);
        __builtin_amdgcn_s_barrier();

        // ph3: stage A1(t+2); counted vmcnt at tile end
        if (t + 2 < NT) STG_H(Aq, bm + 128, k2, Acur + 16384);
        __builtin_amdgcn_s_barrier();
        CLUSTER(1, 1, bf1);
        if (t < NT - 2) {
            asm volatile("s_waitcnt vmcnt(4)" ::: "memory");  // B(t+1) landed; A(t+2) in flight
        } else if (t == NT - 2) {
            asm volatile("s_waitcnt vmcnt(0)" ::: "memory");
        }
        if (t < NT - 1) __builtin_amdgcn_s_barrier();
    }
    #undef CLUSTER
    #undef RD_A
    #undef RD_B
    #undef STG_H

    // ---- epilogue: C/D col = lane&15 (B idx), row = (lane>>4)*4 + j (A idx) ----
    const int r0 = (lane >> 4) * 4;
    float rav[8][4];
    #pragma unroll
    for (int m = 0; m < 8; ++m)
        #pragma unroll
        for (int j = 0; j < 4; ++j)
            rav[m][j] = Ra[bm + wm * 128 + m * 16 + r0 + j];

    #pragma unroll
    for (int n = 0; n < 4; ++n) {
        const int col = bn + wn * 64 + n * 16 + c0;
        const float s = Sw[col];
        #pragma unroll
        for (int m = 0; m < 8; ++m) {
            const int rowb = bm + wm * 128 + m * 16 + r0;
            #pragma unroll
            for (int j = 0; j < 4; ++j)
                Out[(size_t)(rowb + j) * N_DIM + col] = (float)acc[m][n][j] * s * rav[m][j];
        }
    }
}

// ---------------- Fallback (fused bf16, if ws too small) ----------------

constexpr int FBM = 128, FBN = 128, FBK = 64, FPAD = 8;

__global__ __launch_bounds__(256)
void qlinear_fused_kernel(const float* __restrict__ A, const int* __restrict__ Wqi,
                          const float* __restrict__ Sw, float* __restrict__ Out, int M) {
    __shared__ unsigned short Asf[FBM][FBK + FPAD];
    __shared__ unsigned short Bsf[FBN][FBK + FPAD];
    const int tid  = threadIdx.x;
    const int lane = tid & 63;
    const int wid  = tid >> 6;
    const int wm   = wid >> 1;
    const int wn   = wid & 1;
    const int bm = blockIdx.y * FBM;
    const int bn = blockIdx.x * FBN;
    const int rowT = tid >> 4;
    const int kq   = tid & 15;
    f32x4 acc[4][4];
    #pragma unroll
    for (int i = 0; i < 4; ++i)
        #pragma unroll
        for (int j = 0; j < 4; ++j) acc[i][j] = (f32x4){0.f,0.f,0.f,0.f};
    const int c0 = lane & 15;
    const int kg = (lane >> 4) * 8;
    for (int k0 = 0; k0 < K_DIM; k0 += FBK) {
        #pragma unroll
        for (int it = 0; it < 8; ++it) {
            const int r = it * 16 + rowT;
            const f32x4 a4 = *(const f32x4*)(A + (size_t)(bm + r) * K_DIM + k0 + kq * 4);
            u16x4 h;
            h[0]=f32_to_bf16(a4[0]); h[1]=f32_to_bf16(a4[1]);
            h[2]=f32_to_bf16(a4[2]); h[3]=f32_to_bf16(a4[3]);
            *(u16x4*)&Asf[r][kq*4] = h;
        }
        #pragma unroll
        for (int it = 0; it < 8; ++it) {
            const int r = it * 16 + rowT;
            const i32x4 w4 = *(const i32x4*)(Wqi + (size_t)(bn + r) * K_DIM + k0 + kq * 4);
            u16x4 h;
            h[0]=f32_to_bf16((float)w4[0]); h[1]=f32_to_bf16((float)w4[1]);
            h[2]=f32_to_bf16((float)w4[2]); h[3]=f32_to_bf16((float)w4[3]);
            *(u16x4*)&Bsf[r][kq*4] = h;
        }
        __syncthreads();
        #pragma unroll
        for (int ks = 0; ks < 2; ++ks) {
            const int kk = ks * 32 + kg;
            bf16x8 af2[4], bfr[4];
            #pragma unroll
            for (int mf = 0; mf < 4; ++mf)
                af2[mf] = *(const bf16x8*)&Asf[wm*64 + mf*16 + c0][kk];
            #pragma unroll
            for (int nf = 0; nf < 4; ++nf)
                bfr[nf] = *(const bf16x8*)&Bsf[wn*64 + nf*16 + c0][kk];
            #pragma unroll
            for (int mf = 0; mf < 4; ++mf)
                #pragma unroll
                for (int nf = 0; nf < 4; ++nf)
                    acc[mf][nf] = __builtin_amdgcn_mfma_f32_16x16x32_bf16(
                        af2[mf], bfr[nf], acc[mf][nf], 0, 0, 0);
        }
        __syncthreads();
    }
    const int r0 = (lane >> 4) * 4;
    #pragma unroll
    for (int nf = 0; nf < 4; ++nf) {
        const int col = bn + wn*64 + nf*16 + c0;
        const float s = Sw[col];
        #pragma unroll
        for (int mf = 0; mf < 4; ++mf) {
            const int rowb = bm + wm*64 + mf*16 + r0;
            #pragma unroll
            for (int j = 0; j < 4; ++j)
                Out[(size_t)(rowb + j) * N_DIM + col] = acc[mf][nf][j] * s;
        }
    }
}

extern "C" void kernel_launch(void* const* d_in, const int* in_sizes, int n_in,
                              void* d_out, int out_size, void* d_ws, size_t ws_size,
                              hipStream_t stream) {
    const float* inp = (const float*)d_in[0];
    const int*   qw  = (const int*)d_in[1];
    const float* sw  = (const float*)d_in[2];
    float*       out = (float*)d_out;

    const int M = in_sizes[0] / K_DIM;                         // 4096
    const size_t nA = (size_t)M * K_DIM;                       // A elements
    const size_t nW = (size_t)N_DIM * K_DIM;                   // W elements
    const size_t needQ = nA + nW + (size_t)M * sizeof(float);  // ~67 MiB

    if (ws_size >= needQ && (M % BM) == 0) {
        signed char* Aq = (signed char*)d_ws;
        signed char* Wq8 = Aq + nA;
        float*       Ra = (float*)(Wq8 + nW);
        quant_a_kernel<<<M, 256, 0, stream>>>(inp, Aq, Ra);
        cvt_w8_kernel<<<2048, 256, 0, stream>>>(qw, Wq8, (int)(nW / 16));
        dim3 grid((N_DIM / BN) * (M / BM));                    // 768
        gemm_i8_256<<<grid, 512, 0, stream>>>(Aq, Wq8, sw, Ra, out, M);
    } else {
        dim3 grid(N_DIM / FBN, M / FBM);
        qlinear_fused_kernel<<<grid, 256, 0, stream>>>(inp, qw, sw, out, M);
    }
}